// Round 17
// baseline (547.276 us; speedup 1.0000x reference)
//
#include <hip/hip_runtime.h>
#include <hip/hip_bf16.h>

#define BATCH 8
#define CDIM 192
#define HEADS 8
#define CH 24
#define HH 128
#define WW 128
#define NPIX (HH*WW)                  // 16384
#define NELEM (BATCH*CDIM*NPIX)       // 25165824
#define NP4 (NPIX/4)                  // 4096

#define DSLAB 16                      // dots: 16 slabs x 1024 px
#define NJOBS 624                     // 576 cross dots + 24 q self + 24 k self

typedef __attribute__((ext_vector_type(8))) short bf16x8;
typedef __attribute__((ext_vector_type(4))) float f32x4;
typedef __attribute__((ext_vector_type(4))) unsigned int u32x4;
typedef __attribute__((ext_vector_type(8))) unsigned short u16x8;

// ---------------------------------------------------------------------------
// Static pool: t0 (fp32, shared for q/k/v), QB/KB (split-bf16 hi+lo planes),
// V (fp32), misc tail. dots overreads (tile rows 24..31) stay in-pool.
// ---------------------------------------------------------------------------
#define UNIT 100663296ull
__device__ __align__(256) unsigned char g_pool[4 * UNIT + (16u << 20)];

#define OFF_T0   (0 * UNIT)
#define OFF_QB   (1 * UNIT)
#define OFF_KB   (2 * UNIT)
#define OFF_V    (3 * UNIT)
#define OFF_MISC (4 * UNIT)
#define OFF_PART (OFF_MISC)                            // 64*16*624*4 = 2555904
#define OFF_S    (OFF_MISC + 2555904ull)               // 64*624*4   = 159744
#define OFF_M    (OFF_S + 159744ull)                   // 8*192*192*4 = 1179648
#define OFF_MF   (OFF_M + 1179648ull)                  // hi+lo bf16  = 1179648

// round-to-nearest-even fp32 -> bf16 (bit pattern)
__device__ inline unsigned short bf_rne(float x) {
  unsigned u = __float_as_uint(x);
  unsigned r = (u + 0x7fffu + ((u >> 16) & 1u)) >> 16;
  return (unsigned short)r;
}
__device__ inline void f32_split(float x, unsigned short& h, unsigned short& l) {
  h = bf_rne(x);
  float hf = __uint_as_float(((unsigned)h) << 16);
  l = bf_rne(x - hf);
}

// ---------------------------------------------------------------------------
// Weight/M -> A-fragment layout (hi at base, lo at +nb*CDIM*CDIM elems).
// ---------------------------------------------------------------------------
__global__ __launch_bounds__(64) void w_to_frag(const float* __restrict__ W,
                                                unsigned short* __restrict__ F,
                                                int nb) {
  const int b = blockIdx.x / 12, mf = blockIdx.x % 12;
  const int lane = threadIdx.x;
  const int row = mf * 16 + (lane & 15);
  const size_t lo = (size_t)nb * CDIM * CDIM;
#pragma unroll
  for (int ks = 0; ks < 6; ++ks) {
    const int k0 = ks * 32 + (lane >> 4) * 8;
    const float* src = W + ((size_t)b * CDIM + row) * CDIM + k0;
    bf16x8 hv, lv;
#pragma unroll
    for (int j = 0; j < 8; ++j) {
      unsigned short h, l;
      f32_split(src[j], h, l);
      hv[j] = (short)h;
      lv[j] = (short)l;
    }
    const size_t didx = (((size_t)(blockIdx.x) * 6 + ks) * 64 + lane) * 8;
    *(bf16x8*)(F + didx) = hv;
    *(bf16x8*)(F + lo + didx) = lv;
  }
}

// ---------------------------------------------------------------------------
// MFMA GEMM v5: 4 waves = 4 N-quarters; each wave owns ALL M=192, 16 px.
// BN=64, grid (256, 8). Zero conversion redundancy (8 elems/lane/tile),
// acc = 12 x f32x4 = 48 VGPR, A-frags transient per-mi. Proven 2-barrier
// sync schedule. LDS Xs[32][68]; swizzle col ^ ((k>>4)<<4) -> 2-way free.
// Split-bf16: B hi = bit-truncation, lo = rne(residual); A rne hi/lo.
// ---------------------------------------------------------------------------
__global__ __launch_bounds__(256, 2) void mfma_gemm192(
    const float* __restrict__ X,
    const unsigned short* __restrict__ WF, size_t w_lo,
    int w_bstride,
    float* __restrict__ Out) {
  const int bn = blockIdx.x;  // 0..255 (64-px tile)
  const int b = blockIdx.y;
  const int t = threadIdx.x;
  const int lane = t & 63, wn = t >> 6;   // wave = N quarter
  const int kq = lane >> 4;

  __shared__ float Xs[32][68];

  const size_t wbase = (size_t)b * w_bstride;
  const float* Xb = X + (size_t)b * CDIM * NPIX + bn * 64;
  const int col = (wn * 16 + (lane & 15)) ^ ((kq >> 1) << 4);  // swizzled read col
  const int r0 = t >> 4;          // 0..15 staging row
  const int col4 = (t & 15) * 4;  // staging col

  f32x4 acc[12];
#pragma unroll
  for (int mi = 0; mi < 12; ++mi) acc[mi] = (f32x4){0.f, 0.f, 0.f, 0.f};

  for (int ks = 0; ks < 6; ++ks) {
    // stage 32x64 fp32 tile; rows 16..31 column-swizzled by XOR 16
    float4 s0 = *(const float4*)(Xb + (size_t)(ks * 32 + r0) * NPIX + col4);
    float4 s1 = *(const float4*)(Xb + (size_t)(ks * 32 + r0 + 16) * NPIX + col4);
    *(float4*)&Xs[r0][col4] = s0;
    *(float4*)&Xs[r0 + 16][col4 ^ 16] = s1;
    __syncthreads();

    // per-lane B conversion: 8 elems (no cross-wave redundancy)
    u32x4 Bh, Bl;
#pragma unroll
    for (int jp = 0; jp < 4; ++jp) {
      const float x0 = Xs[kq * 8 + 2 * jp][col];
      const float x1 = Xs[kq * 8 + 2 * jp + 1][col];
      const unsigned u0 = __float_as_uint(x0);
      const unsigned u1 = __float_as_uint(x1);
      Bh[jp] = (u1 & 0xffff0000u) | (u0 >> 16);
      const float rr0 = x0 - __uint_as_float(u0 & 0xffff0000u);
      const float rr1 = x1 - __uint_as_float(u1 & 0xffff0000u);
      Bl[jp] = ((unsigned)bf_rne(rr1) << 16) | (unsigned)bf_rne(rr0);
    }
    __syncthreads();
    const bf16x8 bh = __builtin_bit_cast(bf16x8, Bh);
    const bf16x8 bl = __builtin_bit_cast(bf16x8, Bl);

#pragma unroll
    for (int mi = 0; mi < 12; ++mi) {
      const size_t idx = wbase + (((size_t)(mi * 6 + ks)) * 64 + lane) * 8;
      const bf16x8 Ah = *(const bf16x8*)(WF + idx);
      const bf16x8 Al = *(const bf16x8*)(WF + w_lo + idx);
      acc[mi] = __builtin_amdgcn_mfma_f32_16x16x32_bf16(Ah, bh, acc[mi], 0, 0, 0);
      acc[mi] = __builtin_amdgcn_mfma_f32_16x16x32_bf16(Ah, bl, acc[mi], 0, 0, 0);
      acc[mi] = __builtin_amdgcn_mfma_f32_16x16x32_bf16(Al, bh, acc[mi], 0, 0, 0);
    }
  }

  // C/D layout: col = lane&15 (pixel), row = (lane>>4)*4 + reg (och)
  const int ocol = bn * 64 + wn * 16 + (lane & 15);
  const int orow = (lane >> 4) * 4;
#pragma unroll
  for (int mi = 0; mi < 12; ++mi)
#pragma unroll
    for (int r = 0; r < 4; ++r) {
      const int och = mi * 16 + orow + r;
      Out[((size_t)b * CDIM + och) * NPIX + ocol] = acc[mi][r];
    }
}

// ---------------------------------------------------------------------------
// Depthwise 3x3 conv -> fp32 (v path). 8 px/thread.
// ---------------------------------------------------------------------------
__global__ __launch_bounds__(256) void dwconv(const float* __restrict__ In,
                                              const float* __restrict__ Wd,
                                              float* __restrict__ Out) {
  const int idx = blockIdx.x * 256 + threadIdx.x;   // 0..NELEM/8-1
  const int x8 = (idx & 15) * 8;
  const int y = (idx >> 4) & 127;
  const int c = (idx >> 11) % CDIM;
  const int b = idx / (2048 * CDIM);

  const float* base = In + (size_t)(b * CDIM + c) * NPIX;
  float w[9];
#pragma unroll
  for (int i = 0; i < 9; ++i) w[i] = Wd[c * 9 + i];

  float a[8] = {0.f, 0.f, 0.f, 0.f, 0.f, 0.f, 0.f, 0.f};
#pragma unroll
  for (int dy = 0; dy < 3; ++dy) {
    const int yy = y + dy - 1;
    if (yy < 0 || yy > 127) continue;
    const float* row = base + yy * WW;
    const float lf = (x8 > 0) ? row[x8 - 1] : 0.f;
    const float4 m0 = *(const float4*)(row + x8);
    const float4 m1 = *(const float4*)(row + x8 + 4);
    const float rt = (x8 + 8 < WW) ? row[x8 + 8] : 0.f;
    const float w0 = w[dy * 3 + 0], w1 = w[dy * 3 + 1], w2 = w[dy * 3 + 2];
    a[0] += w0 * lf   + w1 * m0.x + w2 * m0.y;
    a[1] += w0 * m0.x + w1 * m0.y + w2 * m0.z;
    a[2] += w0 * m0.y + w1 * m0.z + w2 * m0.w;
    a[3] += w0 * m0.z + w1 * m0.w + w2 * m1.x;
    a[4] += w0 * m0.w + w1 * m1.x + w2 * m1.y;
    a[5] += w0 * m1.x + w1 * m1.y + w2 * m1.z;
    a[6] += w0 * m1.y + w1 * m1.z + w2 * m1.w;
    a[7] += w0 * m1.z + w1 * m1.w + w2 * rt;
  }
  float4 o0, o1;
  o0.x = a[0]; o0.y = a[1]; o0.z = a[2]; o0.w = a[3];
  o1.x = a[4]; o1.y = a[5]; o1.z = a[6]; o1.w = a[7];
  *(float4*)(Out + (size_t)idx * 8) = o0;
  *(float4*)(Out + (size_t)idx * 8 + 4) = o1;
}

// ---------------------------------------------------------------------------
// Depthwise 3x3 conv -> split-bf16 planes (q,k paths). 8 px/thread.
// ---------------------------------------------------------------------------
__global__ __launch_bounds__(256) void dwconv_bf(const float* __restrict__ In,
                                                 const float* __restrict__ Wd,
                                                 unsigned short* __restrict__ Out) {
  const int idx = blockIdx.x * 256 + threadIdx.x;   // 0..NELEM/8-1
  const int x8 = (idx & 15) * 8;
  const int y = (idx >> 4) & 127;
  const int c = (idx >> 11) % CDIM;
  const int b = idx / (2048 * CDIM);

  const float* base = In + (size_t)(b * CDIM + c) * NPIX;
  float w[9];
#pragma unroll
  for (int i = 0; i < 9; ++i) w[i] = Wd[c * 9 + i];

  float a[8] = {0.f, 0.f, 0.f, 0.f, 0.f, 0.f, 0.f, 0.f};
#pragma unroll
  for (int dy = 0; dy < 3; ++dy) {
    const int yy = y + dy - 1;
    if (yy < 0 || yy > 127) continue;
    const float* row = base + yy * WW;
    const float lf = (x8 > 0) ? row[x8 - 1] : 0.f;
    const float4 m0 = *(const float4*)(row + x8);
    const float4 m1 = *(const float4*)(row + x8 + 4);
    const float rt = (x8 + 8 < WW) ? row[x8 + 8] : 0.f;
    const float w0 = w[dy * 3 + 0], w1 = w[dy * 3 + 1], w2 = w[dy * 3 + 2];
    a[0] += w0 * lf   + w1 * m0.x + w2 * m0.y;
    a[1] += w0 * m0.x + w1 * m0.y + w2 * m0.z;
    a[2] += w0 * m0.y + w1 * m0.z + w2 * m0.w;
    a[3] += w0 * m0.z + w1 * m0.w + w2 * m1.x;
    a[4] += w0 * m0.w + w1 * m1.x + w2 * m1.y;
    a[5] += w0 * m1.x + w1 * m1.y + w2 * m1.z;
    a[6] += w0 * m1.y + w1 * m1.z + w2 * m1.w;
    a[7] += w0 * m1.z + w1 * m1.w + w2 * rt;
  }
  u16x8 hv, lv;
#pragma unroll
  for (int j = 0; j < 8; ++j) {
    unsigned short h, l;
    f32_split(a[j], h, l);
    hv[j] = h;
    lv[j] = l;
  }
  *(u16x8*)(Out + (size_t)idx * 8) = hv;
  *(u16x8*)(Out + NELEM + (size_t)idx * 8) = lv;
}

// ---------------------------------------------------------------------------
// MFMA gram with 2-deep register prefetch (R13-proven).
// ---------------------------------------------------------------------------
__global__ __launch_bounds__(256) void dots_mfma(
    const unsigned short* __restrict__ QF,
    const unsigned short* __restrict__ KF,
    float* __restrict__ Part) {
  const int bh = blockIdx.x;
  const int slab = blockIdx.y;          // 0..15
  const int b = bh >> 3, h = bh & 7;
  const int t = threadIdx.x;
  const int lane = t & 63, wid = t >> 6;

  const size_t rowbase = (size_t)(b * CDIM + h * CH);
  const int px0 = slab * 1024 + wid * 256;
  const int rr = lane & 15;
  const int j8 = (lane >> 4) * 8;

  f32x4 accx[2][2], aqq[2], aqhl[2], akk[2], akhl[2];
#pragma unroll
  for (int mi = 0; mi < 2; ++mi) {
#pragma unroll
    for (int ni = 0; ni < 2; ++ni) accx[mi][ni] = (f32x4){0.f, 0.f, 0.f, 0.f};
    aqq[mi] = (f32x4){0.f, 0.f, 0.f, 0.f};
    aqhl[mi] = (f32x4){0.f, 0.f, 0.f, 0.f};
    akk[mi] = (f32x4){0.f, 0.f, 0.f, 0.f};
    akhl[mi] = (f32x4){0.f, 0.f, 0.f, 0.f};
  }

  auto load_step = [&](int s, bf16x8 (&qh)[2], bf16x8 (&ql)[2],
                       bf16x8 (&kh)[2], bf16x8 (&kl)[2]) {
    const int px = px0 + s * 32 + j8;
#pragma unroll
    for (int mi = 0; mi < 2; ++mi) {
      const size_t off = (rowbase + mi * 16 + rr) * (size_t)NPIX + px;
      qh[mi] = *(const bf16x8*)(QF + off);
      ql[mi] = *(const bf16x8*)(QF + NELEM + off);
      kh[mi] = *(const bf16x8*)(KF + off);
      kl[mi] = *(const bf16x8*)(KF + NELEM + off);
    }
  };
  auto mfma_step = [&](bf16x8 (&qh)[2], bf16x8 (&ql)[2], bf16x8 (&kh)[2],
                       bf16x8 (&kl)[2]) {
#pragma unroll
    for (int mi = 0; mi < 2; ++mi) {
#pragma unroll
      for (int ni = 0; ni < 2; ++ni) {
        accx[mi][ni] = __builtin_amdgcn_mfma_f32_16x16x32_bf16(
            qh[mi], kh[ni], accx[mi][ni], 0, 0, 0);
        accx[mi][ni] = __builtin_amdgcn_mfma_f32_16x16x32_bf16(
            qh[mi], kl[ni], accx[mi][ni], 0, 0, 0);
        accx[mi][ni] = __builtin_amdgcn_mfma_f32_16x16x32_bf16(
            ql[mi], kh[ni], accx[mi][ni], 0, 0, 0);
      }
      aqq[mi] = __builtin_amdgcn_mfma_f32_16x16x32_bf16(qh[mi], qh[mi],
                                                        aqq[mi], 0, 0, 0);
      aqhl[mi] = __builtin_amdgcn_mfma_f32_16x16x32_bf16(qh[mi], ql[mi],
                                                         aqhl[mi], 0, 0, 0);
      akk[mi] = __builtin_amdgcn_mfma_f32_16x16x32_bf16(kh[mi], kh[mi],
                                                        akk[mi], 0, 0, 0);
      akhl[mi] = __builtin_amdgcn_mfma_f32_16x16x32_bf16(kh[mi], kl[mi],
                                                         akhl[mi], 0, 0, 0);
    }
  };

  bf16x8 Aqh[2], Aql[2], Akh[2], Akl[2];
  bf16x8 Bqh[2], Bql[2], Bkh[2], Bkl[2];
  load_step(0, Aqh, Aql, Akh, Akl);
#pragma unroll
  for (int s = 0; s < 8; s += 2) {
    if (s + 1 < 8) load_step(s + 1, Bqh, Bql, Bkh, Bkl);
    mfma_step(Aqh, Aql, Akh, Akl);
    if (s + 2 < 8) load_step(s + 2, Aqh, Aql, Akh, Akl);
    mfma_step(Bqh, Bql, Bkh, Bkl);
  }

  // cross-wave reduce via LDS. C layout: col=lane&15, row=(lane>>4)*4+r.
  __shared__ float xls[4][24][24];
  __shared__ float qls[4][24], kls[4][24];
  const int col = lane & 15;
  const int rbase = (lane >> 4) * 4;
#pragma unroll
  for (int mi = 0; mi < 2; ++mi) {
#pragma unroll
    for (int ni = 0; ni < 2; ++ni) {
      const int d = ni * 16 + col;
      if (d < 24) {
#pragma unroll
        for (int r = 0; r < 4; ++r) {
          const int c = mi * 16 + rbase + r;
          if (c < 24) xls[wid][c][d] = accx[mi][ni][r];
        }
      }
    }
    const int cc = mi * 16 + col;
    const int rd = col - rbase;
    if (cc < 24 && rd >= 0 && rd < 4) {
      qls[wid][cc] = aqq[mi][rd] + 2.f * aqhl[mi][rd];
      kls[wid][cc] = akk[mi][rd] + 2.f * akhl[mi][rd];
    }
  }
  __syncthreads();

  float* P = Part + ((size_t)bh * DSLAB + slab) * NJOBS;
  for (int j = t; j < 576; j += 256) {
    const int c = j / 24, d = j % 24;
    P[j] = xls[0][c][d] + xls[1][c][d] + xls[2][c][d] + xls[3][c][d];
  }
  if (t < 24) P[576 + t] = qls[0][t] + qls[1][t] + qls[2][t] + qls[3][t];
  else if (t >= 32 && t < 56) {
    const int c = t - 32;
    P[600 + c] = kls[0][c] + kls[1][c] + kls[2][c] + kls[3][c];
  }
}

__global__ __launch_bounds__(640) void dots_reduce(const float* __restrict__ Part,
                                                   float* __restrict__ S) {
  const int bh = blockIdx.x;
  const int job = threadIdx.x;
  if (job >= NJOBS) return;
  float s = 0.f;
  for (int i = 0; i < DSLAB; ++i)
    s += Part[((size_t)bh * DSLAB + i) * NJOBS + job];
  S[bh * NJOBS + job] = s;
}

// ---------------------------------------------------------------------------
// Normalize, softmax, fold proj: M_b = proj_w @ blockdiag(attn_b).
// ---------------------------------------------------------------------------
__global__ __launch_bounds__(576) void build_M(const float* __restrict__ S,
                                               const float* __restrict__ PW,
                                               const float* __restrict__ Temp,
                                               float* __restrict__ M) {
  const int b = blockIdx.x, h = blockIdx.y;
  const int bh = b * 8 + h;
  __shared__ float att[CH][CH];
  __shared__ float qn[CH], kn[CH];
  const int t = threadIdx.x;
  const float* Sb = S + (size_t)bh * NJOBS;

  if (t < CH) {
    qn[t] = fmaxf(sqrtf(Sb[576 + t]), 1e-12f);
    kn[t] = fmaxf(sqrtf(Sb[600 + t]), 1e-12f);
  }
  __syncthreads();
  const float temp = Temp[h];
  if (t < 576) {
    const int c = t / 24, d = t % 24;
    att[c][d] = Sb[t] / (qn[c] * kn[d]) * temp;
  }
  __syncthreads();
  if (t < CH) {
    float mx = -1e30f;
    for (int d = 0; d < CH; ++d) mx = fmaxf(mx, att[t][d]);
    float sum = 0.f;
    for (int d = 0; d < CH; ++d) {
      const float e = __expf(att[t][d] - mx);
      att[t][d] = e;
      sum += e;
    }
    const float inv = 1.f / sum;
    for (int d = 0; d < CH; ++d) att[t][d] *= inv;
  }
  __syncthreads();
  for (int i = t; i < CDIM * CH; i += 576) {
    const int o = i / CH, d = i % CH;
    float s = 0.f;
#pragma unroll
    for (int c = 0; c < CH; ++c) s += PW[o * CDIM + h * CH + c] * att[c][d];
    M[((size_t)b * CDIM + o) * CDIM + h * CH + d] = s;
  }
}

// ---------------------------------------------------------------------------

extern "C" void kernel_launch(void* const* d_in, const int* in_sizes, int n_in,
                              void* d_out, int out_size, void* d_ws, size_t ws_size,
                              hipStream_t stream) {
  const float* x_feat = (const float*)d_in[0];
  const float* y_feat = (const float*)d_in[1];
  const float* q_pw   = (const float*)d_in[2];
  const float* q_dw   = (const float*)d_in[3];
  const float* k_pw   = (const float*)d_in[4];
  const float* k_dw   = (const float*)d_in[5];
  const float* v_pw   = (const float*)d_in[6];
  const float* v_dw   = (const float*)d_in[7];
  const float* proj_w = (const float*)d_in[8];
  const float* temp   = (const float*)d_in[9];
  float* out = (float*)d_out;

  unsigned char* pool;
  (void)hipGetSymbolAddress((void**)&pool, HIP_SYMBOL(g_pool));
  float* t0 = (float*)(pool + OFF_T0);
  unsigned short* QB = (unsigned short*)(pool + OFF_QB);
  unsigned short* KB = (unsigned short*)(pool + OFF_KB);
  float* v  = (float*)(pool + OFF_V);
  float* part = (float*)(pool + OFF_PART);
  float* S    = (float*)(pool + OFF_S);
  float* M    = (float*)(pool + OFF_M);
  unsigned short* MF = (unsigned short*)(pool + OFF_MF);

  unsigned short* WQF = MF + 2ull * 8 * CDIM * CDIM;
  unsigned short* WKF = WQF + 2ull * CDIM * CDIM;
  unsigned short* WVF = WKF + 2ull * CDIM * CDIM;

  const size_t w1_lo = (size_t)1 * CDIM * CDIM;
  const size_t w8_lo = (size_t)8 * CDIM * CDIM;

  const dim3 ggrid(NPIX / 64, BATCH);    // (256, 8) -> M=192, BN=64
  const int dwgrid = (NELEM / 8) / 256;  // 12288 (8 px/thread)

  // weight conversions (tiny)
  w_to_frag<<<12, 64, 0, stream>>>(q_pw, WQF, 1);
  w_to_frag<<<12, 64, 0, stream>>>(k_pw, WKF, 1);
  w_to_frag<<<12, 64, 0, stream>>>(v_pw, WVF, 1);

  // producer->consumer adjacency; single t0 reused (stays L3-hot)
  mfma_gemm192<<<ggrid, 256, 0, stream>>>(x_feat, WQF, w1_lo, 0, t0);
  dwconv_bf<<<dwgrid, 256, 0, stream>>>(t0, q_dw, QB);
  mfma_gemm192<<<ggrid, 256, 0, stream>>>(y_feat, WKF, w1_lo, 0, t0);
  dwconv_bf<<<dwgrid, 256, 0, stream>>>(t0, k_dw, KB);

  // MFMA gram + softmax + proj fold
  dots_mfma<<<dim3(64, DSLAB), 256, 0, stream>>>(QB, KB, part);
  dots_reduce<<<64, 640, 0, stream>>>(part, S);
  build_M<<<dim3(BATCH, HEADS), 576, 0, stream>>>(S, proj_w, temp, M);
  w_to_frag<<<8 * 12, 64, 0, stream>>>(M, MF, 8);

  // v path right before its consumer
  mfma_gemm192<<<ggrid, 256, 0, stream>>>(y_feat, WVF, w1_lo, 0, t0);
  dwconv<<<dwgrid, 256, 0, stream>>>(t0, v_dw, v);

  // out = M_b @ v (v L3-hot)
  mfma_gemm192<<<ggrid, 256, 0, stream>>>(v, MF, w8_lo, CDIM * CDIM, out);
}

// Round 18
// 415.216 us; speedup vs baseline: 1.3180x; 1.3180x over previous
//
#include <hip/hip_runtime.h>
#include <hip/hip_bf16.h>

#define BATCH 8
#define CDIM 192
#define HEADS 8
#define CH 24
#define HH 128
#define WW 128
#define NPIX (HH*WW)                  // 16384
#define NELEM (BATCH*CDIM*NPIX)       // 25165824
#define NP4 (NPIX/4)                  // 4096

#define DSLAB 16                      // dots: 16 slabs x 1024 px
#define NJOBS 624                     // 576 cross dots + 24 q self + 24 k self

typedef __attribute__((ext_vector_type(8))) short bf16x8;
typedef __attribute__((ext_vector_type(4))) float f32x4;
typedef __attribute__((ext_vector_type(4))) unsigned int u32x4;
typedef __attribute__((ext_vector_type(8))) unsigned short u16x8;

// ---------------------------------------------------------------------------
// Static pool: t0 (fp32, shared for q/k/v), QB/KB (split-bf16 hi+lo planes),
// V (fp32), misc tail. dots overreads (tile rows 24..31) stay in-pool.
// ---------------------------------------------------------------------------
#define UNIT 100663296ull
__device__ __align__(256) unsigned char g_pool[4 * UNIT + (16u << 20)];

#define OFF_T0   (0 * UNIT)
#define OFF_QB   (1 * UNIT)
#define OFF_KB   (2 * UNIT)
#define OFF_V    (3 * UNIT)
#define OFF_MISC (4 * UNIT)
#define OFF_PART (OFF_MISC)                            // 64*16*624*4 = 2555904
#define OFF_M    (OFF_MISC + 2555904ull)               // 8*192*192*4 = 1179648
#define OFF_MF   (OFF_M + 1179648ull)                  // hi+lo bf16  = 1179648

// round-to-nearest-even fp32 -> bf16 (bit pattern)
__device__ inline unsigned short bf_rne(float x) {
  unsigned u = __float_as_uint(x);
  unsigned r = (u + 0x7fffu + ((u >> 16) & 1u)) >> 16;
  return (unsigned short)r;
}
__device__ inline void f32_split(float x, unsigned short& h, unsigned short& l) {
  h = bf_rne(x);
  float hf = __uint_as_float(((unsigned)h) << 16);
  l = bf_rne(x - hf);
}

// ---------------------------------------------------------------------------
// Weight/M -> A-fragment layout (hi at base, lo at +nb*CDIM*CDIM elems).
// ---------------------------------------------------------------------------
__device__ inline void w_frag_body(const float* W, unsigned short* F, int nb,
                                   int bidx, int lane) {
  const int b = bidx / 12, mf = bidx % 12;
  const int row = mf * 16 + (lane & 15);
  const size_t lo = (size_t)nb * CDIM * CDIM;
#pragma unroll
  for (int ks = 0; ks < 6; ++ks) {
    const int k0 = ks * 32 + (lane >> 4) * 8;
    const float* src = W + ((size_t)b * CDIM + row) * CDIM + k0;
    bf16x8 hv, lv;
#pragma unroll
    for (int j = 0; j < 8; ++j) {
      unsigned short h, l;
      f32_split(src[j], h, l);
      hv[j] = (short)h;
      lv[j] = (short)l;
    }
    const size_t didx = (((size_t)bidx * 6 + ks) * 64 + lane) * 8;
    *(bf16x8*)(F + didx) = hv;
    *(bf16x8*)(F + lo + didx) = lv;
  }
}

__global__ __launch_bounds__(64) void w_to_frag(const float* __restrict__ W,
                                                unsigned short* __restrict__ F,
                                                int nb) {
  w_frag_body(W, F, nb, blockIdx.x, threadIdx.x);
}

// merged q/k/v weight conversion (36 blocks: 12 per tensor)
__global__ __launch_bounds__(64) void w_to_frag3(
    const float* __restrict__ WQ, const float* __restrict__ WK,
    const float* __restrict__ WV, unsigned short* __restrict__ FQ,
    unsigned short* __restrict__ FK, unsigned short* __restrict__ FV) {
  const int ts = blockIdx.x / 12;
  const int bidx = blockIdx.x % 12;
  const float* W = (ts == 0) ? WQ : (ts == 1) ? WK : WV;
  unsigned short* F = (ts == 0) ? FQ : (ts == 1) ? FK : FV;
  w_frag_body(W, F, 1, bidx, threadIdx.x);
}

// ---------------------------------------------------------------------------
// MFMA GEMM, M=192 per block (R15-proven sync version).
// Split-bf16: B hi = bit-truncation, lo = rne(residual); A rne hi/lo.
// ---------------------------------------------------------------------------
__global__ __launch_bounds__(256, 2) void mfma_gemm192(
    const float* __restrict__ X,
    const unsigned short* __restrict__ WF, size_t w_lo,
    int w_bstride,
    float* __restrict__ Out) {
  const int bn = blockIdx.x;  // 0..127 pixel tile (one image row)
  const int b = blockIdx.y;
  const int t = threadIdx.x;
  const int lane = t & 63, wid = t >> 6;
  const int wm = wid >> 1, wn = wid & 1;
  const int kq = lane >> 4;

  __shared__ float Xs[32][132];

  const size_t wbase = (size_t)b * w_bstride;
  const float* Xb = X + (size_t)b * CDIM * NPIX;
  const int col4 = (t & 31) * 4;
  const int r0 = t >> 5;
  const int pxl = wn * 64 + (lane & 15);

  f32x4 acc[6][4];
#pragma unroll
  for (int mi = 0; mi < 6; ++mi)
#pragma unroll
    for (int ni = 0; ni < 4; ++ni) acc[mi][ni] = (f32x4){0.f, 0.f, 0.f, 0.f};

  for (int ks = 0; ks < 6; ++ks) {
    float4 st[4];
#pragma unroll
    for (int p = 0; p < 4; ++p)
      st[p] = *(const float4*)(Xb + (size_t)(ks * 32 + r0 + 8 * p) * NPIX +
                               bn * 128 + col4);
#pragma unroll
    for (int p = 0; p < 4; ++p)
      *(float4*)&Xs[r0 + 8 * p][col4 ^ ((p & 1) << 4)] = st[p];
    __syncthreads();

    bf16x8 Ah[6], Al[6];
#pragma unroll
    for (int mi = 0; mi < 6; ++mi) {
      const int mf = wm * 6 + mi;
      const size_t idx = wbase + (((size_t)(mf * 6 + ks)) * 64 + lane) * 8;
      Ah[mi] = *(const bf16x8*)(WF + idx);
      Al[mi] = *(const bf16x8*)(WF + w_lo + idx);
    }

    u32x4 Bh[4], Bl[4];
#pragma unroll
    for (int ni = 0; ni < 4; ++ni) {
      const int pxs = (pxl + ni * 16) ^ ((kq & 1) << 4);
#pragma unroll
      for (int jp = 0; jp < 4; ++jp) {
        const float x0 = Xs[kq * 8 + 2 * jp][pxs];
        const float x1 = Xs[kq * 8 + 2 * jp + 1][pxs];
        const unsigned u0 = __float_as_uint(x0);
        const unsigned u1 = __float_as_uint(x1);
        Bh[ni][jp] = (u1 & 0xffff0000u) | (u0 >> 16);
        const float rr0 = x0 - __uint_as_float(u0 & 0xffff0000u);
        const float rr1 = x1 - __uint_as_float(u1 & 0xffff0000u);
        Bl[ni][jp] = ((unsigned)bf_rne(rr1) << 16) | (unsigned)bf_rne(rr0);
      }
    }
    __syncthreads();

#pragma unroll
    for (int mi = 0; mi < 6; ++mi)
#pragma unroll
      for (int ni = 0; ni < 4; ++ni) {
        const bf16x8 bh = __builtin_bit_cast(bf16x8, Bh[ni]);
        const bf16x8 bl = __builtin_bit_cast(bf16x8, Bl[ni]);
        acc[mi][ni] = __builtin_amdgcn_mfma_f32_16x16x32_bf16(
            Ah[mi], bh, acc[mi][ni], 0, 0, 0);
        acc[mi][ni] = __builtin_amdgcn_mfma_f32_16x16x32_bf16(
            Ah[mi], bl, acc[mi][ni], 0, 0, 0);
        acc[mi][ni] = __builtin_amdgcn_mfma_f32_16x16x32_bf16(
            Al[mi], bh, acc[mi][ni], 0, 0, 0);
      }
  }

  const int ocol = bn * 128 + wn * 64 + (lane & 15);
  const int orow = wm * 96 + (lane >> 4) * 4;
#pragma unroll
  for (int mi = 0; mi < 6; ++mi)
#pragma unroll
    for (int r = 0; r < 4; ++r) {
      const int och = orow + mi * 16 + r;
      float* dst = Out + ((size_t)b * CDIM + och) * NPIX + ocol;
#pragma unroll
      for (int ni = 0; ni < 4; ++ni) dst[ni * 16] = acc[mi][ni][r];
    }
}

// ---------------------------------------------------------------------------
// Depthwise 3x3 conv -> fp32 (v path). 8 px/thread.
// ---------------------------------------------------------------------------
__global__ __launch_bounds__(256) void dwconv(const float* __restrict__ In,
                                              const float* __restrict__ Wd,
                                              float* __restrict__ Out) {
  const int idx = blockIdx.x * 256 + threadIdx.x;   // 0..NELEM/8-1
  const int x8 = (idx & 15) * 8;
  const int y = (idx >> 4) & 127;
  const int c = (idx >> 11) % CDIM;
  const int b = idx / (2048 * CDIM);

  const float* base = In + (size_t)(b * CDIM + c) * NPIX;
  float w[9];
#pragma unroll
  for (int i = 0; i < 9; ++i) w[i] = Wd[c * 9 + i];

  float a[8] = {0.f, 0.f, 0.f, 0.f, 0.f, 0.f, 0.f, 0.f};
#pragma unroll
  for (int dy = 0; dy < 3; ++dy) {
    const int yy = y + dy - 1;
    if (yy < 0 || yy > 127) continue;
    const float* row = base + yy * WW;
    const float lf = (x8 > 0) ? row[x8 - 1] : 0.f;
    const float4 m0 = *(const float4*)(row + x8);
    const float4 m1 = *(const float4*)(row + x8 + 4);
    const float rt = (x8 + 8 < WW) ? row[x8 + 8] : 0.f;
    const float w0 = w[dy * 3 + 0], w1 = w[dy * 3 + 1], w2 = w[dy * 3 + 2];
    a[0] += w0 * lf   + w1 * m0.x + w2 * m0.y;
    a[1] += w0 * m0.x + w1 * m0.y + w2 * m0.z;
    a[2] += w0 * m0.y + w1 * m0.z + w2 * m0.w;
    a[3] += w0 * m0.z + w1 * m0.w + w2 * m1.x;
    a[4] += w0 * m0.w + w1 * m1.x + w2 * m1.y;
    a[5] += w0 * m1.x + w1 * m1.y + w2 * m1.z;
    a[6] += w0 * m1.y + w1 * m1.z + w2 * m1.w;
    a[7] += w0 * m1.z + w1 * m1.w + w2 * rt;
  }
  float4 o0, o1;
  o0.x = a[0]; o0.y = a[1]; o0.z = a[2]; o0.w = a[3];
  o1.x = a[4]; o1.y = a[5]; o1.z = a[6]; o1.w = a[7];
  *(float4*)(Out + (size_t)idx * 8) = o0;
  *(float4*)(Out + (size_t)idx * 8 + 4) = o1;
}

// ---------------------------------------------------------------------------
// Depthwise 3x3 conv -> split-bf16 planes (q,k paths). 8 px/thread.
// ---------------------------------------------------------------------------
__global__ __launch_bounds__(256) void dwconv_bf(const float* __restrict__ In,
                                                 const float* __restrict__ Wd,
                                                 unsigned short* __restrict__ Out) {
  const int idx = blockIdx.x * 256 + threadIdx.x;   // 0..NELEM/8-1
  const int x8 = (idx & 15) * 8;
  const int y = (idx >> 4) & 127;
  const int c = (idx >> 11) % CDIM;
  const int b = idx / (2048 * CDIM);

  const float* base = In + (size_t)(b * CDIM + c) * NPIX;
  float w[9];
#pragma unroll
  for (int i = 0; i < 9; ++i) w[i] = Wd[c * 9 + i];

  float a[8] = {0.f, 0.f, 0.f, 0.f, 0.f, 0.f, 0.f, 0.f};
#pragma unroll
  for (int dy = 0; dy < 3; ++dy) {
    const int yy = y + dy - 1;
    if (yy < 0 || yy > 127) continue;
    const float* row = base + yy * WW;
    const float lf = (x8 > 0) ? row[x8 - 1] : 0.f;
    const float4 m0 = *(const float4*)(row + x8);
    const float4 m1 = *(const float4*)(row + x8 + 4);
    const float rt = (x8 + 8 < WW) ? row[x8 + 8] : 0.f;
    const float w0 = w[dy * 3 + 0], w1 = w[dy * 3 + 1], w2 = w[dy * 3 + 2];
    a[0] += w0 * lf   + w1 * m0.x + w2 * m0.y;
    a[1] += w0 * m0.x + w1 * m0.y + w2 * m0.z;
    a[2] += w0 * m0.y + w1 * m0.z + w2 * m0.w;
    a[3] += w0 * m0.z + w1 * m0.w + w2 * m1.x;
    a[4] += w0 * m0.w + w1 * m1.x + w2 * m1.y;
    a[5] += w0 * m1.x + w1 * m1.y + w2 * m1.z;
    a[6] += w0 * m1.y + w1 * m1.z + w2 * m1.w;
    a[7] += w0 * m1.z + w1 * m1.w + w2 * rt;
  }
  u16x8 hv, lv;
#pragma unroll
  for (int j = 0; j < 8; ++j) {
    unsigned short h, l;
    f32_split(a[j], h, l);
    hv[j] = h;
    lv[j] = l;
  }
  *(u16x8*)(Out + (size_t)idx * 8) = hv;
  *(u16x8*)(Out + NELEM + (size_t)idx * 8) = lv;
}

// ---------------------------------------------------------------------------
// MFMA gram with 2-deep register prefetch (R13-proven).
// ---------------------------------------------------------------------------
__global__ __launch_bounds__(256) void dots_mfma(
    const unsigned short* __restrict__ QF,
    const unsigned short* __restrict__ KF,
    float* __restrict__ Part) {
  const int bh = blockIdx.x;
  const int slab = blockIdx.y;          // 0..15
  const int b = bh >> 3, h = bh & 7;
  const int t = threadIdx.x;
  const int lane = t & 63, wid = t >> 6;

  const size_t rowbase = (size_t)(b * CDIM + h * CH);
  const int px0 = slab * 1024 + wid * 256;
  const int rr = lane & 15;
  const int j8 = (lane >> 4) * 8;

  f32x4 accx[2][2], aqq[2], aqhl[2], akk[2], akhl[2];
#pragma unroll
  for (int mi = 0; mi < 2; ++mi) {
#pragma unroll
    for (int ni = 0; ni < 2; ++ni) accx[mi][ni] = (f32x4){0.f, 0.f, 0.f, 0.f};
    aqq[mi] = (f32x4){0.f, 0.f, 0.f, 0.f};
    aqhl[mi] = (f32x4){0.f, 0.f, 0.f, 0.f};
    akk[mi] = (f32x4){0.f, 0.f, 0.f, 0.f};
    akhl[mi] = (f32x4){0.f, 0.f, 0.f, 0.f};
  }

  auto load_step = [&](int s, bf16x8 (&qh)[2], bf16x8 (&ql)[2],
                       bf16x8 (&kh)[2], bf16x8 (&kl)[2]) {
    const int px = px0 + s * 32 + j8;
#pragma unroll
    for (int mi = 0; mi < 2; ++mi) {
      const size_t off = (rowbase + mi * 16 + rr) * (size_t)NPIX + px;
      qh[mi] = *(const bf16x8*)(QF + off);
      ql[mi] = *(const bf16x8*)(QF + NELEM + off);
      kh[mi] = *(const bf16x8*)(KF + off);
      kl[mi] = *(const bf16x8*)(KF + NELEM + off);
    }
  };
  auto mfma_step = [&](bf16x8 (&qh)[2], bf16x8 (&ql)[2], bf16x8 (&kh)[2],
                       bf16x8 (&kl)[2]) {
#pragma unroll
    for (int mi = 0; mi < 2; ++mi) {
#pragma unroll
      for (int ni = 0; ni < 2; ++ni) {
        accx[mi][ni] = __builtin_amdgcn_mfma_f32_16x16x32_bf16(
            qh[mi], kh[ni], accx[mi][ni], 0, 0, 0);
        accx[mi][ni] = __builtin_amdgcn_mfma_f32_16x16x32_bf16(
            qh[mi], kl[ni], accx[mi][ni], 0, 0, 0);
        accx[mi][ni] = __builtin_amdgcn_mfma_f32_16x16x32_bf16(
            ql[mi], kh[ni], accx[mi][ni], 0, 0, 0);
      }
      aqq[mi] = __builtin_amdgcn_mfma_f32_16x16x32_bf16(qh[mi], qh[mi],
                                                        aqq[mi], 0, 0, 0);
      aqhl[mi] = __builtin_amdgcn_mfma_f32_16x16x32_bf16(qh[mi], ql[mi],
                                                         aqhl[mi], 0, 0, 0);
      akk[mi] = __builtin_amdgcn_mfma_f32_16x16x32_bf16(kh[mi], kh[mi],
                                                        akk[mi], 0, 0, 0);
      akhl[mi] = __builtin_amdgcn_mfma_f32_16x16x32_bf16(kh[mi], kl[mi],
                                                         akhl[mi], 0, 0, 0);
    }
  };

  bf16x8 Aqh[2], Aql[2], Akh[2], Akl[2];
  bf16x8 Bqh[2], Bql[2], Bkh[2], Bkl[2];
  load_step(0, Aqh, Aql, Akh, Akl);
#pragma unroll
  for (int s = 0; s < 8; s += 2) {
    if (s + 1 < 8) load_step(s + 1, Bqh, Bql, Bkh, Bkl);
    mfma_step(Aqh, Aql, Akh, Akl);
    if (s + 2 < 8) load_step(s + 2, Aqh, Aql, Akh, Akl);
    mfma_step(Bqh, Bql, Bkh, Bkl);
  }

  // cross-wave reduce via LDS. C layout: col=lane&15, row=(lane>>4)*4+r.
  __shared__ float xls[4][24][24];
  __shared__ float qls[4][24], kls[4][24];
  const int col = lane & 15;
  const int rbase = (lane >> 4) * 4;
#pragma unroll
  for (int mi = 0; mi < 2; ++mi) {
#pragma unroll
    for (int ni = 0; ni < 2; ++ni) {
      const int d = ni * 16 + col;
      if (d < 24) {
#pragma unroll
        for (int r = 0; r < 4; ++r) {
          const int c = mi * 16 + rbase + r;
          if (c < 24) xls[wid][c][d] = accx[mi][ni][r];
        }
      }
    }
    const int cc = mi * 16 + col;
    const int rd = col - rbase;
    if (cc < 24 && rd >= 0 && rd < 4) {
      qls[wid][cc] = aqq[mi][rd] + 2.f * aqhl[mi][rd];
      kls[wid][cc] = akk[mi][rd] + 2.f * akhl[mi][rd];
    }
  }
  __syncthreads();

  float* P = Part + ((size_t)bh * DSLAB + slab) * NJOBS;
  for (int j = t; j < 576; j += 256) {
    const int c = j / 24, d = j % 24;
    P[j] = xls[0][c][d] + xls[1][c][d] + xls[2][c][d] + xls[3][c][d];
  }
  if (t < 24) P[576 + t] = qls[0][t] + qls[1][t] + qls[2][t] + qls[3][t];
  else if (t >= 32 && t < 56) {
    const int c = t - 32;
    P[600 + c] = kls[0][c] + kls[1][c] + kls[2][c] + kls[3][c];
  }
}

// ---------------------------------------------------------------------------
// Slab-reduce + normalize + softmax + fold proj: M_b = proj_w @ blockdiag(attn).
// (dots_reduce folded in: each thread sums its job's 16 slab partials.)
// ---------------------------------------------------------------------------
__global__ __launch_bounds__(576) void build_M(const float* __restrict__ Part,
                                               const float* __restrict__ PW,
                                               const float* __restrict__ Temp,
                                               float* __restrict__ M) {
  const int b = blockIdx.x, h = blockIdx.y;
  const int bh = b * 8 + h;
  __shared__ float att[CH][CH];
  __shared__ float qn[CH], kn[CH];
  const int t = threadIdx.x;
  const float* Pb = Part + (size_t)bh * DSLAB * NJOBS;

  auto slabsum = [&](int job) {
    float s = 0.f;
#pragma unroll
    for (int i = 0; i < DSLAB; ++i) s += Pb[(size_t)i * NJOBS + job];
    return s;
  };

  if (t < CH) {
    qn[t] = fmaxf(sqrtf(slabsum(576 + t)), 1e-12f);
    kn[t] = fmaxf(sqrtf(slabsum(600 + t)), 1e-12f);
  }
  __syncthreads();
  const float temp = Temp[h];
  if (t < 576) {
    const int c = t / 24, d = t % 24;
    att[c][d] = slabsum(t) / (qn[c] * kn[d]) * temp;
  }
  __syncthreads();
  if (t < CH) {
    float mx = -1e30f;
    for (int d = 0; d < CH; ++d) mx = fmaxf(mx, att[t][d]);
    float sum = 0.f;
    for (int d = 0; d < CH; ++d) {
      const float e = __expf(att[t][d] - mx);
      att[t][d] = e;
      sum += e;
    }
    const float inv = 1.f / sum;
    for (int d = 0; d < CH; ++d) att[t][d] *= inv;
  }
  __syncthreads();
  for (int i = t; i < CDIM * CH; i += 576) {
    const int o = i / CH, d = i % CH;
    float s = 0.f;
#pragma unroll
    for (int c = 0; c < CH; ++c) s += PW[o * CDIM + h * CH + c] * att[c][d];
    M[((size_t)b * CDIM + o) * CDIM + h * CH + d] = s;
  }
}

// ---------------------------------------------------------------------------

extern "C" void kernel_launch(void* const* d_in, const int* in_sizes, int n_in,
                              void* d_out, int out_size, void* d_ws, size_t ws_size,
                              hipStream_t stream) {
  const float* x_feat = (const float*)d_in[0];
  const float* y_feat = (const float*)d_in[1];
  const float* q_pw   = (const float*)d_in[2];
  const float* q_dw   = (const float*)d_in[3];
  const float* k_pw   = (const float*)d_in[4];
  const float* k_dw   = (const float*)d_in[5];
  const float* v_pw   = (const float*)d_in[6];
  const float* v_dw   = (const float*)d_in[7];
  const float* proj_w = (const float*)d_in[8];
  const float* temp   = (const float*)d_in[9];
  float* out = (float*)d_out;

  unsigned char* pool;
  (void)hipGetSymbolAddress((void**)&pool, HIP_SYMBOL(g_pool));
  float* t0 = (float*)(pool + OFF_T0);
  unsigned short* QB = (unsigned short*)(pool + OFF_QB);
  unsigned short* KB = (unsigned short*)(pool + OFF_KB);
  float* v  = (float*)(pool + OFF_V);
  float* part = (float*)(pool + OFF_PART);
  float* M    = (float*)(pool + OFF_M);
  unsigned short* MF = (unsigned short*)(pool + OFF_MF);

  unsigned short* WQF = MF + 2ull * 8 * CDIM * CDIM;
  unsigned short* WKF = WQF + 2ull * CDIM * CDIM;
  unsigned short* WVF = WKF + 2ull * CDIM * CDIM;

  const size_t w1_lo = (size_t)1 * CDIM * CDIM;
  const size_t w8_lo = (size_t)8 * CDIM * CDIM;

  const dim3 ggrid(NPIX / 128, BATCH);   // (128, 8) -> M=192 per block
  const int dwgrid = (NELEM / 8) / 256;  // 12288 (8 px/thread)

  // all three weight conversions in one tiny dispatch
  w_to_frag3<<<36, 64, 0, stream>>>(q_pw, k_pw, v_pw, WQF, WKF, WVF);

  // producer->consumer adjacency; single t0 reused (stays L3-hot)
  mfma_gemm192<<<ggrid, 256, 0, stream>>>(x_feat, WQF, w1_lo, 0, t0);
  dwconv_bf<<<dwgrid, 256, 0, stream>>>(t0, q_dw, QB);
  mfma_gemm192<<<ggrid, 256, 0, stream>>>(y_feat, WKF, w1_lo, 0, t0);
  dwconv_bf<<<dwgrid, 256, 0, stream>>>(t0, k_dw, KB);

  // MFMA gram + (slab-reduce + softmax + proj fold)
  dots_mfma<<<dim3(64, DSLAB), 256, 0, stream>>>(QB, KB, part);
  build_M<<<dim3(BATCH, HEADS), 576, 0, stream>>>(part, proj_w, temp, M);
  w_to_frag<<<8 * 12, 64, 0, stream>>>(M, MF, 8);

  // v path right before its consumer
  mfma_gemm192<<<ggrid, 256, 0, stream>>>(y_feat, WVF, w1_lo, 0, t0);
  dwconv<<<dwgrid, 256, 0, stream>>>(t0, v_dw, v);

  // out = M_b @ v (v L3-hot)
  mfma_gemm192<<<ggrid, 256, 0, stream>>>(v, MF, w8_lo, CDIM * CDIM, out);
}